// Round 1
// baseline (774.738 us; speedup 1.0000x reference)
//
#include <hip/hip_runtime.h>

// Problem constants
#define NTOK 49          // window tokens (7x7)
#define NW   64          // number of distinct masks
#define SCALEQ 0.17677669529663687f   // 32^-0.5

typedef __bf16 bf16;
typedef __bf16 bf16x8 __attribute__((ext_vector_type(8)));
typedef float  f32x4  __attribute__((ext_vector_type(4)));

// ---- LDS layout (units: bf16 elements) ----
// qs : [8][49][40]  q, pre-scaled            off 0      (15680)
// ks : [8][49][40]  k                        off 15680  (15680)
// vts: [8][32][56]  v transposed [dd][m], m pad 49..55 zeroed  off 31360 (14336)
// un : union region off 45696:
//        xs  [49][264]  staged x (phase 0/1)          12936
//        Pb  8 x [49][72] per-wave P buffers (phase 2) 28224
//        ost [49][264]  attention output (phase 3/4)  12936
// total = 45696 + 28224 = 73920 elems = 147840 B  (< 160 KiB, 1 block/CU)
#define QS_OFF   0
#define KS_OFF   15680
#define VTS_OFF  31360
#define UN_OFF   45696
#define P_STRIDE 3528            // 49*72
#define SMEM_ELEMS 73920
#define SMEM_BYTES (SMEM_ELEMS*2)
static_assert(SMEM_BYTES == 147840, "lds budget");

// Prep: convert weights to bf16, expand relative-position bias to [8][49][49]
__global__ __launch_bounds__(256) void prep_kernel(
    const float* __restrict__ qkv_w, const float* __restrict__ proj_w,
    const float* __restrict__ bias_table, const int* __restrict__ rel_index,
    bf16* __restrict__ wq, bf16* __restrict__ wp, float* __restrict__ bias_full)
{
  int i = blockIdx.x * 256 + threadIdx.x;
  if (i < 768*256) wq[i] = (bf16)qkv_w[i];
  if (i < 256*256) wp[i] = (bf16)proj_w[i];
  if (i < 8*49*49) {
    int h  = i / 2401;
    int nm = i - h*2401;
    bias_full[i] = bias_table[rel_index[nm]*8 + h];
  }
}

__global__ void __launch_bounds__(512, 2)
win_attn_kernel(const float* __restrict__ x,
                const float* __restrict__ mask,
                const float* __restrict__ qkv_b,
                const float* __restrict__ proj_b,
                const bf16*  __restrict__ wq,
                const bf16*  __restrict__ wp,
                const float* __restrict__ bias_full,
                float* __restrict__ out)
{
  extern __shared__ bf16 smem[];
  const int b    = blockIdx.x;
  const int tid  = threadIdx.x;
  const int wave = tid >> 6;
  const int lane = tid & 63;
  const int quad = lane >> 4;
  const int l16  = lane & 15;
  const int w    = b & (NW - 1);   // mask window index: b = outer*64 + w

  bf16* qs  = smem + QS_OFF;
  bf16* ks  = smem + KS_OFF;
  bf16* vts = smem + VTS_OFF;
  bf16* xs  = smem + UN_OFF;                      // [49][264]
  bf16* Pb  = smem + UN_OFF + wave * P_STRIDE;    // per-wave [49][72]

  f32x4 zero4 = {0.f, 0.f, 0.f, 0.f};

  // ---------- phase 0: stage x -> bf16 LDS; zero vts pad rows ----------
  const float* xw = x + (size_t)b * (NTOK*256);
  for (int i = tid; i < NTOK*256; i += 512) {
    int n = i >> 8, c = i & 255;
    xs[n*264 + c] = (bf16)xw[i];
  }
  for (int i = tid; i < 8*32*7; i += 512) {        // vts m in [49,56) := 0
    int h = i / 224, r = i - h*224;
    int dd = r / 7, mm = 49 + (r - dd*7);
    vts[(h*32 + dd)*56 + mm] = (bf16)0.0f;
  }
  __syncthreads();

  // ---------- phase 1: qkv = x @ Wqkv^T + b; route into qs/ks/vts ----------
  {
    bf16x8 afr[4][8];                 // a-frags for all 4 row tiles x 8 ksteps
#pragma unroll
    for (int tr = 0; tr < 4; ++tr) {
      int m = tr*16 + l16; if (m > 48) m = 48;     // clamp: rows>=49 discarded
      const bf16* arow = xs + m*264 + quad*8;
#pragma unroll
      for (int kk = 0; kk < 8; ++kk)
        afr[tr][kk] = *(const bf16x8*)(arow + kk*32);
    }
#pragma unroll 1
    for (int tci = 0; tci < 6; ++tci) {            // wave owns col tiles wave*6..+5
      int jcol = (wave*6 + tci)*16 + l16;          // 0..767
      const bf16* wrow = wq + jcol*256 + quad*8;
      f32x4 acc[4];
#pragma unroll
      for (int tr = 0; tr < 4; ++tr) acc[tr] = zero4;
#pragma unroll
      for (int kk = 0; kk < 8; ++kk) {
        bf16x8 bfr = *(const bf16x8*)(wrow + kk*32);
#pragma unroll
        for (int tr = 0; tr < 4; ++tr)
          acc[tr] = __builtin_amdgcn_mfma_f32_16x16x32_bf16(afr[tr][kk], bfr, acc[tr], 0,0,0);
      }
      float bj = qkv_b[jcol];
      int s  = jcol >> 8;
      int hh = (jcol >> 5) & 7;
      int dd = jcol & 31;
#pragma unroll
      for (int tr = 0; tr < 4; ++tr) {
#pragma unroll
        for (int rg = 0; rg < 4; ++rg) {
          int row = tr*16 + quad*4 + rg;           // C layout: row=quad*4+reg
          if (row < 49) {
            float v = acc[tr][rg] + bj;
            if (s == 0)      qs[(hh*49 + row)*40 + dd] = (bf16)(v * SCALEQ);
            else if (s == 1) ks[(hh*49 + row)*40 + dd] = (bf16)v;
            else             vts[(hh*32 + dd)*56 + row] = (bf16)v;
          }
        }
      }
    }
  }
  __syncthreads();

  // ---------- phase 2: attention, wave = head ----------
  f32x4 O[4][2];
  {
    const int h = wave;
    const bf16* qh = qs  + h*49*40;
    const bf16* kh = ks  + h*49*40;
    const bf16* vh = vts + h*32*56;

    bf16x8 qf[4], kf[4];
#pragma unroll
    for (int t = 0; t < 4; ++t) {
      int m = t*16 + l16; if (m > 48) m = 48;
      qf[t] = *(const bf16x8*)(qh + m*40 + quad*8);   // A: [m=lane&15][k=quad*8+j]
      kf[t] = *(const bf16x8*)(kh + m*40 + quad*8);   // B: [n=lane&15][k=quad*8+j]
    }
    f32x4 S[4][4];
#pragma unroll
    for (int tr = 0; tr < 4; ++tr)
#pragma unroll
      for (int tc = 0; tc < 4; ++tc)
        S[tr][tc] = __builtin_amdgcn_mfma_f32_16x16x32_bf16(qf[tr], kf[tc], zero4, 0,0,0);

    const float* bh = bias_full + h*2401;
    const float* mw = mask + w*2401;
#pragma unroll
    for (int tr = 0; tr < 4; ++tr) {
#pragma unroll
      for (int rg = 0; rg < 4; ++rg) {
        int row = tr*16 + quad*4 + rg;
#pragma unroll
        for (int tc = 0; tc < 4; ++tc) {
          int col = tc*16 + l16;
          float v = S[tr][tc][rg];
          if (col >= 49) v = -1e30f;                 // pad cols -> exact 0 after exp
          else if (row < 49) {
            int idx = row*49 + col;
            v += bh[idx] + mw[idx];
          }
          S[tr][tc][rg] = v;
        }
        // softmax over row: 4 in-lane cols x 16 lanes of this quad group
        float mx = fmaxf(fmaxf(S[tr][0][rg], S[tr][1][rg]),
                         fmaxf(S[tr][2][rg], S[tr][3][rg]));
#pragma unroll
        for (int off = 1; off < 16; off <<= 1)
          mx = fmaxf(mx, __shfl_xor(mx, off));
        float sum = 0.f;
#pragma unroll
        for (int tc = 0; tc < 4; ++tc) {
          float p = __expf(S[tr][tc][rg] - mx);
          S[tr][tc][rg] = p;
          sum += p;
        }
#pragma unroll
        for (int off = 1; off < 16; off <<= 1)
          sum += __shfl_xor(sum, off);
        float inv = 1.f / sum;
        if (row < 49) {                              // rows>=49 never stored
#pragma unroll
          for (int tc = 0; tc < 4; ++tc)
            Pb[row*72 + tc*16 + l16] = (bf16)(S[tr][tc][rg] * inv);
        }
      }
    }

    // O = P @ V   (P via LDS round-trip C-layout -> A-layout)
#pragma unroll
    for (int tr = 0; tr < 4; ++tr) { O[tr][0] = zero4; O[tr][1] = zero4; }
#pragma unroll
    for (int kst = 0; kst < 2; ++kst) {
      int mc  = kst*32 + quad*8;
      int mcv = (mc >= 56) ? 0 : mc;                 // P cols 56..63 are 0 -> any finite v ok
      bf16x8 vf0 = *(const bf16x8*)(vh + l16*56 + mcv);
      bf16x8 vf1 = *(const bf16x8*)(vh + (16 + l16)*56 + mcv);
#pragma unroll
      for (int tr = 0; tr < 4; ++tr) {
        int row = tr*16 + l16; if (row > 48) row = 48;
        bf16x8 pf = *(const bf16x8*)(Pb + row*72 + mc);
        O[tr][0] = __builtin_amdgcn_mfma_f32_16x16x32_bf16(pf, vf0, O[tr][0], 0,0,0);
        O[tr][1] = __builtin_amdgcn_mfma_f32_16x16x32_bf16(pf, vf1, O[tr][1], 0,0,0);
      }
    }
  }
  __syncthreads();                                   // all P reads done before aliasing

  // ---------- phase 3: O -> ost [49][264] (token-major, channel = h*32+dd) ----------
  bf16* ost = smem + UN_OFF;
  {
    const int h = wave;
#pragma unroll
    for (int tr = 0; tr < 4; ++tr)
#pragma unroll
      for (int rg = 0; rg < 4; ++rg) {
        int row = tr*16 + quad*4 + rg;
        if (row < 49) {
          ost[row*264 + h*32 + l16]      = (bf16)O[tr][0][rg];
          ost[row*264 + h*32 + 16 + l16] = (bf16)O[tr][1][rg];
        }
      }
  }
  __syncthreads();

  // ---------- phase 4: out = ost @ Wproj^T + b ----------
  {
    bf16x8 afr[4][8];
#pragma unroll
    for (int tr = 0; tr < 4; ++tr) {
      int m = tr*16 + l16; if (m > 48) m = 48;
      const bf16* arow = ost + m*264 + quad*8;
#pragma unroll
      for (int kk = 0; kk < 8; ++kk)
        afr[tr][kk] = *(const bf16x8*)(arow + kk*32);
    }
    float* ob = out + (size_t)b * (NTOK*256);
#pragma unroll 1
    for (int tci = 0; tci < 2; ++tci) {              // wave owns out-col tiles wave*2..+1
      int ocol = (wave*2 + tci)*16 + l16;            // 0..255
      const bf16* wrow = wp + ocol*256 + quad*8;
      f32x4 acc[4];
#pragma unroll
      for (int tr = 0; tr < 4; ++tr) acc[tr] = zero4;
#pragma unroll
      for (int kk = 0; kk < 8; ++kk) {
        bf16x8 bfr = *(const bf16x8*)(wrow + kk*32);
#pragma unroll
        for (int tr = 0; tr < 4; ++tr)
          acc[tr] = __builtin_amdgcn_mfma_f32_16x16x32_bf16(afr[tr][kk], bfr, acc[tr], 0,0,0);
      }
      float bj = proj_b[ocol];
#pragma unroll
      for (int tr = 0; tr < 4; ++tr)
#pragma unroll
        for (int rg = 0; rg < 4; ++rg) {
          int row = tr*16 + quad*4 + rg;
          if (row < 49) ob[row*256 + ocol] = acc[tr][rg] + bj;
        }
    }
  }
}

extern "C" void kernel_launch(void* const* d_in, const int* in_sizes, int n_in,
                              void* d_out, int out_size, void* d_ws, size_t ws_size,
                              hipStream_t stream) {
  const float* x          = (const float*)d_in[0];
  const float* mask       = (const float*)d_in[1];
  const float* qkv_w      = (const float*)d_in[2];
  const float* qkv_b      = (const float*)d_in[3];
  const float* proj_w     = (const float*)d_in[4];
  const float* proj_b     = (const float*)d_in[5];
  const float* bias_table = (const float*)d_in[6];
  const int*   rel_index  = (const int*)d_in[7];
  float* out = (float*)d_out;

  // workspace: wq bf16 [768*256] | wp bf16 [256*256] | bias_full f32 [8*49*49]
  bf16*  wq        = (bf16*)d_ws;
  bf16*  wp        = wq + 768*256;
  float* bias_full = (float*)((char*)d_ws + 524288);

  prep_kernel<<<768, 256, 0, stream>>>(qkv_w, proj_w, bias_table, rel_index,
                                       wq, wp, bias_full);

  (void)hipFuncSetAttribute(reinterpret_cast<const void*>(&win_attn_kernel),
                            hipFuncAttributeMaxDynamicSharedMemorySize, SMEM_BYTES);
  win_attn_kernel<<<4096, 512, SMEM_BYTES, stream>>>(
      x, mask, qkv_b, proj_b, wq, wp, bias_full, out);
}

// Round 2
// 737.967 us; speedup vs baseline: 1.0498x; 1.0498x over previous
//
#include <hip/hip_runtime.h>

// Problem constants
#define NTOK 49          // window tokens (7x7)
#define NW   64          // number of distinct masks
#define SCALEQ 0.17677669529663687f   // 32^-0.5

typedef __bf16 bf16;
typedef __bf16 bf16x4 __attribute__((ext_vector_type(4)));
typedef __bf16 bf16x8 __attribute__((ext_vector_type(8)));
typedef float  f32x4  __attribute__((ext_vector_type(4)));

// ---- LDS layout (units: bf16 elements) ----
// qs : [8][49][40]  q, pre-scaled            off 0      (15680)
// ks : [8][49][40]  k                        off 15680  (15680)
// vts: [8][32][56]  v transposed [dd][m], m pad 49..55 zeroed  off 31360 (14336)
// un : union region off 45696:
//        xs  [49][264]  staged x (phase 0/1)            12936
//        Pb  8 x [49][72] per-HEAD P buffers (phase 2)  28224
//        ost [49][264]  attention output (phase 3/4)    12936
// total = 45696 + 28224 = 73920 elems = 147840 B  (1 block/CU, 16 waves)
#define QS_OFF   0
#define KS_OFF   15680
#define VTS_OFF  31360
#define UN_OFF   45696
#define P_STRIDE 3528            // 49*72
#define SMEM_ELEMS 73920
#define SMEM_BYTES (SMEM_ELEMS*2)
static_assert(SMEM_BYTES == 147840, "lds budget");

// Prep: convert weights to bf16, expand relative-position bias to [8][49][49]
__global__ __launch_bounds__(256) void prep_kernel(
    const float* __restrict__ qkv_w, const float* __restrict__ proj_w,
    const float* __restrict__ bias_table, const int* __restrict__ rel_index,
    bf16* __restrict__ wq, bf16* __restrict__ wp, float* __restrict__ bias_full)
{
  int i = blockIdx.x * 256 + threadIdx.x;
  if (i < 768*256) wq[i] = (bf16)qkv_w[i];
  if (i < 256*256) wp[i] = (bf16)proj_w[i];
  if (i < 8*49*49) {
    int h  = i / 2401;
    int nm = i - h*2401;
    bias_full[i] = bias_table[rel_index[nm]*8 + h];
  }
}

__global__ void __launch_bounds__(1024)
win_attn_kernel(const float* __restrict__ x,
                const float* __restrict__ mask,
                const float* __restrict__ qkv_b,
                const float* __restrict__ proj_b,
                const bf16*  __restrict__ wq,
                const bf16*  __restrict__ wp,
                const float* __restrict__ bias_full,
                float* __restrict__ out)
{
  extern __shared__ bf16 smem[];
  const int b    = blockIdx.x;
  const int tid  = threadIdx.x;
  const int wave = tid >> 6;      // 0..15
  const int lane = tid & 63;
  const int quad = lane >> 4;
  const int l16  = lane & 15;
  const int w    = b & (NW - 1);   // mask window index

  bf16* qs  = smem + QS_OFF;
  bf16* ks  = smem + KS_OFF;
  bf16* vts = smem + VTS_OFF;
  bf16* xs  = smem + UN_OFF;                      // [49][264]

  f32x4 zero4 = {0.f, 0.f, 0.f, 0.f};

  // ---------- phase 0: stage x -> bf16 LDS (float4 loads); zero vts pad ----------
  {
    const float4* xv = (const float4*)(x + (size_t)b * (NTOK*256));  // 3136 vec4
    for (int i = tid; i < NTOK*64; i += 1024) {
      float4 v = xv[i];
      int n = i >> 6, c = (i & 63) * 4;
      bf16x4 pk = {(bf16)v.x, (bf16)v.y, (bf16)v.z, (bf16)v.w};
      *(bf16x4*)(xs + n*264 + c) = pk;
    }
    for (int i = tid; i < 8*32*7; i += 1024) {       // vts m in [49,56) := 0
      int h = i / 224, r = i - h*224;
      int dd = r / 7, mm = 49 + (r - dd*7);
      vts[(h*32 + dd)*56 + mm] = (bf16)0.0f;
    }
  }
  __syncthreads();

  // ---------- phase 1: qkv = x @ Wqkv^T + b; route into qs/ks/vts ----------
  // 48 col tiles, wave owns tiles wave*3 .. wave*3+2. kk-outer, acc live.
  {
    f32x4 acc[3][4];
#pragma unroll
    for (int t = 0; t < 3; ++t)
#pragma unroll
      for (int tr = 0; tr < 4; ++tr) acc[t][tr] = zero4;

    int jc0 = (wave*3)*16 + l16;
    const bf16* w0 = wq + (size_t)jc0*256 + quad*8;
#pragma unroll
    for (int kk = 0; kk < 8; ++kk) {
      bf16x8 afr[4];
#pragma unroll
      for (int tr = 0; tr < 4; ++tr) {
        int m = tr*16 + l16; if (m > 48) m = 48;     // clamp: rows>=49 discarded
        afr[tr] = *(const bf16x8*)(xs + m*264 + quad*8 + kk*32);
      }
#pragma unroll
      for (int t = 0; t < 3; ++t) {
        bf16x8 bfr = *(const bf16x8*)(w0 + (size_t)t*16*256 + kk*32);
#pragma unroll
        for (int tr = 0; tr < 4; ++tr)
          acc[t][tr] = __builtin_amdgcn_mfma_f32_16x16x32_bf16(afr[tr], bfr, acc[t][tr], 0,0,0);
      }
    }
#pragma unroll
    for (int t = 0; t < 3; ++t) {
      int jcol = (wave*3 + t)*16 + l16;              // 0..767
      float bj = qkv_b[jcol];
      int s  = jcol >> 8;
      int hh = (jcol >> 5) & 7;
      int dd = jcol & 31;
#pragma unroll
      for (int tr = 0; tr < 4; ++tr) {
#pragma unroll
        for (int rg = 0; rg < 4; ++rg) {
          int row = tr*16 + quad*4 + rg;             // C layout: row=quad*4+reg
          if (row < 49) {
            float v = acc[t][tr][rg] + bj;
            if (s == 0)      qs[(hh*49 + row)*40 + dd] = (bf16)(v * SCALEQ);
            else if (s == 1) ks[(hh*49 + row)*40 + dd] = (bf16)v;
            else             vts[(hh*32 + dd)*56 + row] = (bf16)v;
          }
        }
      }
    }
  }
  __syncthreads();

  // ---------- phase 2: attention; wave pair per head (h=wave>>1, half=wave&1) ----------
  f32x4 O[2][2];
  {
    const int h    = wave >> 1;
    const int half = wave & 1;
    const bf16* qh = qs  + h*49*40;
    const bf16* kh = ks  + h*49*40;
    const bf16* vh = vts + h*32*56;
    bf16* Pb = smem + UN_OFF + h * P_STRIDE;        // per-head [49][72]

    bf16x8 qf[2], kf[4];
#pragma unroll
    for (int t = 0; t < 2; ++t) {
      int m = (half*2 + t)*16 + l16; if (m > 48) m = 48;
      qf[t] = *(const bf16x8*)(qh + m*40 + quad*8);  // A: [m=lane&15][k=quad*8+j]
    }
#pragma unroll
    for (int t = 0; t < 4; ++t) {
      int m = t*16 + l16; if (m > 48) m = 48;
      kf[t] = *(const bf16x8*)(kh + m*40 + quad*8);  // B: [n=lane&15][k=quad*8+j]
    }
    f32x4 S[2][4];
#pragma unroll
    for (int tr = 0; tr < 2; ++tr)
#pragma unroll
      for (int tc = 0; tc < 4; ++tc)
        S[tr][tc] = __builtin_amdgcn_mfma_f32_16x16x32_bf16(qf[tr], kf[tc], zero4, 0,0,0);

    const float* bh = bias_full + h*2401;
    const float* mw = mask + w*2401;
#pragma unroll
    for (int tr2 = 0; tr2 < 2; ++tr2) {
      int tr = half*2 + tr2;
#pragma unroll
      for (int rg = 0; rg < 4; ++rg) {
        int row = tr*16 + quad*4 + rg;
#pragma unroll
        for (int tc = 0; tc < 4; ++tc) {
          int col = tc*16 + l16;
          float v = S[tr2][tc][rg];
          if (col >= 49) v = -1e30f;                 // pad cols -> exact 0 after exp
          else if (row < 49) {
            int idx = row*49 + col;
            v += bh[idx] + mw[idx];
          }
          S[tr2][tc][rg] = v;
        }
        float mx = fmaxf(fmaxf(S[tr2][0][rg], S[tr2][1][rg]),
                         fmaxf(S[tr2][2][rg], S[tr2][3][rg]));
#pragma unroll
        for (int off = 1; off < 16; off <<= 1)
          mx = fmaxf(mx, __shfl_xor(mx, off));
        float sum = 0.f;
#pragma unroll
        for (int tc = 0; tc < 4; ++tc) {
          float p = __expf(S[tr2][tc][rg] - mx);
          S[tr2][tc][rg] = p;
          sum += p;
        }
#pragma unroll
        for (int off = 1; off < 16; off <<= 1)
          sum += __shfl_xor(sum, off);
        float inv = 1.f / sum;
        if (row < 49) {                              // rows>=49 never stored
#pragma unroll
          for (int tc = 0; tc < 4; ++tc)
            Pb[row*72 + tc*16 + l16] = (bf16)(S[tr2][tc][rg] * inv);
        }
      }
    }

    // O = P @ V   (wave reads only rows of its own tiles -> no barrier needed)
#pragma unroll
    for (int tr = 0; tr < 2; ++tr) { O[tr][0] = zero4; O[tr][1] = zero4; }
#pragma unroll
    for (int kst = 0; kst < 2; ++kst) {
      int mc  = kst*32 + quad*8;
      int mcv = (mc >= 56) ? 0 : mc;                 // P cols 56..63 are 0
      bf16x8 vf0 = *(const bf16x8*)(vh + l16*56 + mcv);
      bf16x8 vf1 = *(const bf16x8*)(vh + (16 + l16)*56 + mcv);
#pragma unroll
      for (int tr2 = 0; tr2 < 2; ++tr2) {
        int row = (half*2 + tr2)*16 + l16; if (row > 48) row = 48;
        bf16x8 pf = *(const bf16x8*)(Pb + row*72 + mc);
        O[tr2][0] = __builtin_amdgcn_mfma_f32_16x16x32_bf16(pf, vf0, O[tr2][0], 0,0,0);
        O[tr2][1] = __builtin_amdgcn_mfma_f32_16x16x32_bf16(pf, vf1, O[tr2][1], 0,0,0);
      }
    }
  }
  __syncthreads();                                   // all P reads done before aliasing

  // ---------- phase 3: O -> ost [49][264] (token-major, channel = h*32+dd) ----------
  bf16* ost = smem + UN_OFF;
  {
    const int h    = wave >> 1;
    const int half = wave & 1;
#pragma unroll
    for (int tr2 = 0; tr2 < 2; ++tr2)
#pragma unroll
      for (int rg = 0; rg < 4; ++rg) {
        int row = (half*2 + tr2)*16 + quad*4 + rg;
        if (row < 49) {
          ost[row*264 + h*32 + l16]      = (bf16)O[tr2][0][rg];
          ost[row*264 + h*32 + 16 + l16] = (bf16)O[tr2][1][rg];
        }
      }
  }
  __syncthreads();

  // ---------- phase 4: out = ost @ Wproj^T + b; wave owns one 16-col tile ----------
  {
    f32x4 acc[4];
#pragma unroll
    for (int tr = 0; tr < 4; ++tr) acc[tr] = zero4;
    int ocol = wave*16 + l16;                        // 0..255
    const bf16* wrow = wp + (size_t)ocol*256 + quad*8;
#pragma unroll
    for (int kk = 0; kk < 8; ++kk) {
      bf16x8 bfr = *(const bf16x8*)(wrow + kk*32);
#pragma unroll
      for (int tr = 0; tr < 4; ++tr) {
        int m = tr*16 + l16; if (m > 48) m = 48;
        bf16x8 afr = *(const bf16x8*)(ost + m*264 + quad*8 + kk*32);
        acc[tr] = __builtin_amdgcn_mfma_f32_16x16x32_bf16(afr, bfr, acc[tr], 0,0,0);
      }
    }
    float bj = proj_b[ocol];
    float* ob = out + (size_t)b * (NTOK*256);
#pragma unroll
    for (int tr = 0; tr < 4; ++tr)
#pragma unroll
      for (int rg = 0; rg < 4; ++rg) {
        int row = tr*16 + quad*4 + rg;
        if (row < 49) ob[row*256 + ocol] = acc[tr][rg] + bj;
      }
  }
}

extern "C" void kernel_launch(void* const* d_in, const int* in_sizes, int n_in,
                              void* d_out, int out_size, void* d_ws, size_t ws_size,
                              hipStream_t stream) {
  const float* x          = (const float*)d_in[0];
  const float* mask       = (const float*)d_in[1];
  const float* qkv_w      = (const float*)d_in[2];
  const float* qkv_b      = (const float*)d_in[3];
  const float* proj_w     = (const float*)d_in[4];
  const float* proj_b     = (const float*)d_in[5];
  const float* bias_table = (const float*)d_in[6];
  const int*   rel_index  = (const int*)d_in[7];
  float* out = (float*)d_out;

  // workspace: wq bf16 [768*256] | wp bf16 [256*256] | bias_full f32 [8*49*49]
  bf16*  wq        = (bf16*)d_ws;
  bf16*  wp        = wq + 768*256;
  float* bias_full = (float*)((char*)d_ws + 524288);

  prep_kernel<<<768, 256, 0, stream>>>(qkv_w, proj_w, bias_table, rel_index,
                                       wq, wp, bias_full);

  (void)hipFuncSetAttribute(reinterpret_cast<const void*>(&win_attn_kernel),
                            hipFuncAttributeMaxDynamicSharedMemorySize, SMEM_BYTES);
  win_attn_kernel<<<4096, 1024, SMEM_BYTES, stream>>>(
      x, mask, qkv_b, proj_b, wq, wp, bias_full, out);
}